// Round 3
// baseline (324.975 us; speedup 1.0000x reference)
//
#include <hip/hip_runtime.h>
#include <hip/hip_bf16.h>

#define S_LEN 1024
#define NB 8
#define NC 768
#define NH 8
#define HD 96
#define NMLP 3072
#define SC (S_LEN*NC)        // 786432
#define BS (NB*S_LEN)        // 8192

typedef __attribute__((ext_vector_type(8))) unsigned short u16x8;
typedef __attribute__((ext_vector_type(4))) unsigned short u16x4;
typedef __attribute__((ext_vector_type(8))) __bf16 bf16x8;
typedef __attribute__((ext_vector_type(4))) float f32x4;

__device__ __forceinline__ unsigned short f2b(float f) {
  union { __hip_bfloat16 h; unsigned short u; } cvt;
  cvt.h = __float2bfloat16(f);
  return cvt.u;
}

// async global->LDS, 16B per lane. LDS dest = wave-uniform base + lane*16.
__device__ __forceinline__ void gload16(const unsigned short* g, unsigned short* l) {
  __builtin_amdgcn_global_load_lds(
      (const __attribute__((address_space(1))) unsigned int*)g,
      (__attribute__((address_space(3))) unsigned int*)l, 16, 0, 0);
}

// overflow-safe tanh-form GELU (abs err < 3e-4 vs exact erf GELU)
__device__ __forceinline__ float gelu_f(float v) {
  float u = v * (0.7978845608f + 0.0356774081f * v * v);
  float au = fabsf(u);
  float e = __expf(-2.0f * au);
  float th = (1.0f - e) / (1.0f + e);
  th = copysignf(th, u);
  return 0.5f * v * (1.0f + th);
}

// ---------------------------------------------------------------------------
// Pipelined bf16 MFMA GEMM: C = A(MxK) * B(KxN), B given TRANSPOSED (Bt: NxK).
// BM=128, BN=256, BK=64. 8 waves (2M x 4N), per-wave 64x64 output (acc[4][4]).
// 3-buffer LDS ring (144 KB): compute tile t from buf t%3 while tile t+1 is
// resident and tile t+2 streams in via global_load_lds. End-of-tile wait is
// s_waitcnt vmcnt(6) (counted, never 0 in steady state) + raw s_barrier.
// LDS XOR-swizzle: 16B chunk index ^= (row&7); inverse-swizzled global source,
// swizzled ds_read_b128 (both-sides involution).
// EPI: 0 = store bf16; 2 = +bias,GELU,bf16; 3 = +residual,f32; 4 = +bias+res,f32
// ---------------------------------------------------------------------------
template<int EPI>
__global__ __launch_bounds__(512, 1)
void gemm8(const unsigned short* __restrict__ A, int lda,
           const unsigned short* __restrict__ Bt, int ldb,
           void* __restrict__ Cv, int ldc, int K,
           const float* __restrict__ bias,
           const float* __restrict__ residual, int ldr)
{
  __shared__ unsigned short As[3*8192];    // 3 x [128][64] bf16 (swizzled rows)
  __shared__ unsigned short Bs[3*16384];   // 3 x [256][64] bf16
  const int tid = threadIdx.x, lane = tid & 63, wid = tid >> 6;
  const int wm = wid & 1, wn = wid >> 1;
  const int r15 = lane & 15, g = lane >> 4;
  const int tm = blockIdx.x * 128, tn = blockIdx.y * 256;
  const int NT = K >> 6;

  // staging source (inverse-swizzled): lane l covers LDS row wid*8+(l>>3),
  // 16B chunk (l&7); global chunk = (l&7) ^ (l>>3).
  const int srow = lane >> 3;
  const int scol = ((lane & 7) ^ srow) << 3;
  const unsigned short* Ag = A  + (size_t)(tm + wid*8 + srow)*lda + scol;
  const unsigned short* Bg = Bt + (size_t)(tn + wid*8 + srow)*ldb + scol;

  // swizzled read offsets (bytes within a 128B row)
  const int kx  = (r15 & 7) << 4;
  const int k0b = (g*16) ^ kx;
  const int k1b = (64 + g*16) ^ kx;
  char* AsB = (char*)As;
  char* BsB = (char*)Bs;
  const int arow = (wm*64 + r15) * 128;
  const int brow = (wn*64 + r15) * 128;

#define LDA8(m,ks) (*(const bf16x8*)(AsB + bufA + arow + (m)*2048 + ((ks) ? k1b : k0b)))
#define LDB8(n,ks) (*(const bf16x8*)(BsB + bufB + brow + (n)*2048 + ((ks) ? k1b : k0b)))
#define STGA(j,kk,bf) gload16(Ag + (size_t)((j)*64)*lda + (kk), As + (bf)*8192  + (j)*4096 + wid*512)
#define STGB(j,kk,bf) gload16(Bg + (size_t)((j)*64)*ldb + (kk), Bs + (bf)*16384 + (j)*4096 + wid*512)

  f32x4 acc[4][4];
  #pragma unroll
  for (int m = 0; m < 4; ++m)
    #pragma unroll
    for (int n = 0; n < 4; ++n)
      acc[m][n] = (f32x4){0.f, 0.f, 0.f, 0.f};

  // prologue: stage tiles 0 and 1; wait for tile 0 (newest 6 = tile1 stay in flight)
  STGA(0,0,0); STGA(1,0,0); STGB(0,0,0); STGB(1,0,0); STGB(2,0,0); STGB(3,0,0);
  STGA(0,64,1); STGA(1,64,1); STGB(0,64,1); STGB(1,64,1); STGB(2,64,1); STGB(3,64,1);
  asm volatile("s_waitcnt vmcnt(6)" ::: "memory");
  __builtin_amdgcn_s_barrier();

  int buf = 0, nbuf = 2;
  for (int t = 0; t < NT; ++t) {
    const int kk = (t + 2) << 6;
    const bool pre = (t + 2) < NT;
    const int bufA = buf * 16384;   // bytes
    const int bufB = buf * 32768;
    bf16x8 a0[2][2], a1[2][2], b0[2][2], b1[2][2];

    // ---- phase 0: stage A halves of tile t+2; compute quadrant (m01, n01)
    if (pre) { STGA(0,kk,nbuf); STGA(1,kk,nbuf); }
    #pragma unroll
    for (int m = 0; m < 2; ++m) { a0[m][0] = LDA8(m,0); a0[m][1] = LDA8(m,1); }
    #pragma unroll
    for (int n = 0; n < 2; ++n) { b0[n][0] = LDB8(n,0); b0[n][1] = LDB8(n,1); }
    __builtin_amdgcn_s_setprio(1);
    #pragma unroll
    for (int m = 0; m < 2; ++m)
      #pragma unroll
      for (int n = 0; n < 2; ++n) {
        acc[m][n] = __builtin_amdgcn_mfma_f32_16x16x32_bf16(a0[m][0], b0[n][0], acc[m][n], 0,0,0);
        acc[m][n] = __builtin_amdgcn_mfma_f32_16x16x32_bf16(a0[m][1], b0[n][1], acc[m][n], 0,0,0);
      }
    __builtin_amdgcn_s_setprio(0);

    // ---- phase 1: stage B halves 0-1; quadrant (m01, n23)
    if (pre) { STGB(0,kk,nbuf); STGB(1,kk,nbuf); }
    #pragma unroll
    for (int n = 0; n < 2; ++n) { b1[n][0] = LDB8(n+2,0); b1[n][1] = LDB8(n+2,1); }
    __builtin_amdgcn_s_setprio(1);
    #pragma unroll
    for (int m = 0; m < 2; ++m)
      #pragma unroll
      for (int n = 0; n < 2; ++n) {
        acc[m][n+2] = __builtin_amdgcn_mfma_f32_16x16x32_bf16(a0[m][0], b1[n][0], acc[m][n+2], 0,0,0);
        acc[m][n+2] = __builtin_amdgcn_mfma_f32_16x16x32_bf16(a0[m][1], b1[n][1], acc[m][n+2], 0,0,0);
      }
    __builtin_amdgcn_s_setprio(0);

    // ---- phase 2: stage B halves 2-3; quadrant (m23, n23)
    if (pre) { STGB(2,kk,nbuf); STGB(3,kk,nbuf); }
    #pragma unroll
    for (int m = 0; m < 2; ++m) { a1[m][0] = LDA8(m+2,0); a1[m][1] = LDA8(m+2,1); }
    __builtin_amdgcn_s_setprio(1);
    #pragma unroll
    for (int m = 0; m < 2; ++m)
      #pragma unroll
      for (int n = 0; n < 2; ++n) {
        acc[m+2][n+2] = __builtin_amdgcn_mfma_f32_16x16x32_bf16(a1[m][0], b1[n][0], acc[m+2][n+2], 0,0,0);
        acc[m+2][n+2] = __builtin_amdgcn_mfma_f32_16x16x32_bf16(a1[m][1], b1[n][1], acc[m+2][n+2], 0,0,0);
      }
    __builtin_amdgcn_s_setprio(0);

    // ---- phase 3: quadrant (m23, n01), reuse b0
    __builtin_amdgcn_s_setprio(1);
    #pragma unroll
    for (int m = 0; m < 2; ++m)
      #pragma unroll
      for (int n = 0; n < 2; ++n) {
        acc[m+2][n] = __builtin_amdgcn_mfma_f32_16x16x32_bf16(a1[m][0], b0[n][0], acc[m+2][n], 0,0,0);
        acc[m+2][n] = __builtin_amdgcn_mfma_f32_16x16x32_bf16(a1[m][1], b0[n][1], acc[m+2][n], 0,0,0);
      }
    __builtin_amdgcn_s_setprio(0);

    // ---- end of tile: counted wait (tile t+1 landed; t+2's 6 stay in flight)
    if (pre) asm volatile("s_waitcnt vmcnt(6)" ::: "memory");
    else     asm volatile("s_waitcnt vmcnt(0)" ::: "memory");
    __builtin_amdgcn_s_barrier();
    buf  = (buf  == 2) ? 0 : buf  + 1;
    nbuf = (nbuf == 2) ? 0 : nbuf + 1;
  }
#undef LDA8
#undef LDB8
#undef STGA
#undef STGB

  unsigned short* Cu = (unsigned short*)Cv;
  float* Cf = (float*)Cv;
  #pragma unroll
  for (int m = 0; m < 4; ++m) {
    #pragma unroll
    for (int n = 0; n < 4; ++n) {
      const int col = tn + wn*64 + n*16 + r15;
      #pragma unroll
      for (int r = 0; r < 4; ++r) {
        const int row = tm + wm*64 + m*16 + g*4 + r;
        float v = acc[m][n][r];
        if (EPI == 2 || EPI == 4) v += bias[col];
        if (EPI == 3 || EPI == 4) v += residual[(size_t)row*ldr + col];
        if (EPI == 2) v = gelu_f(v);
        if (EPI == 0 || EPI == 2) Cu[(size_t)row*ldc + col] = f2b(v);
        else                      Cf[(size_t)row*ldc + col] = v;
      }
    }
  }
}

// ---------------------------------------------------------------------------
// Flash attention, one (b,h) x 128-q-row tile per block, 4 waves.
// ---------------------------------------------------------------------------
__global__ __launch_bounds__(256, 2)
void flash_attn(const unsigned short* __restrict__ qkv,   // [B][S][2304] bf16
                const unsigned short* __restrict__ vt,    // [B*H][96][1024] bf16
                unsigned short* __restrict__ outb)        // [B][S][768] bf16
{
  __shared__ unsigned short Ks[128*96];
  __shared__ unsigned short Vs[96*128];
  __shared__ unsigned short Ps[128*128];
  const int tid = threadIdx.x, lane = tid & 63, wq = tid >> 6;
  const int r15 = lane & 15, g = lane >> 4;
  const int bh = blockIdx.y, b = bh >> 3, h = bh & 7;
  const int q0 = blockIdx.x * 128;
  const int swz = (r15 & 7) << 4;
  char* PsB = (char*)Ps;
  char* VsB = (char*)Vs;

  bf16x8 qf[2][3];
  {
    const unsigned short* qb = qkv + ((size_t)b*S_LEN + q0 + wq*32 + r15)*2304 + h*HD + g*8;
    #pragma unroll
    for (int n = 0; n < 2; ++n)
      #pragma unroll
      for (int kc = 0; kc < 3; ++kc)
        qf[n][kc] = *(const bf16x8*)(qb + (size_t)n*16*2304 + kc*32);
  }

  int krow[6], kcol[6], vrow[6], vcol[6];
  #pragma unroll
  for (int i = 0; i < 6; ++i) {
    const int c = (wq*6 + i)*64 + lane;
    krow[i] = c / 12;
    kcol[i] = (c % 12) * 8;
    const int L = c * 16;
    const int row = L >> 8, cb = L & 255;
    vrow[i] = row;
    vcol[i] = (cb ^ ((row & 7) << 4)) >> 1;
  }
  const unsigned short* kbase = qkv + (size_t)b*S_LEN*2304 + NC + h*HD;
  const unsigned short* vbase = vt + (size_t)bh*HD*S_LEN;

  f32x4 oacc[6][2];
  #pragma unroll
  for (int m = 0; m < 6; ++m) {
    oacc[m][0] = (f32x4){0.f,0.f,0.f,0.f};
    oacc[m][1] = (f32x4){0.f,0.f,0.f,0.f};
  }
  float mrun[2] = {-INFINITY, -INFINITY};
  float lrun[2] = {0.f, 0.f};

  for (int kt = 0; kt < 8; ++kt) {
    const unsigned short* ksrc = kbase + (size_t)kt*128*2304;
    const unsigned short* vsrc = vbase + kt*128;
    #pragma unroll
    for (int i = 0; i < 6; ++i) {
      gload16(ksrc + (size_t)krow[i]*2304 + kcol[i], Ks + (wq*6 + i)*512);
      gload16(vsrc + vrow[i]*1024 + vcol[i],         Vs + (wq*6 + i)*512);
    }
    __syncthreads();

    f32x4 sacc[8][2];
    #pragma unroll
    for (int m = 0; m < 8; ++m) {
      sacc[m][0] = (f32x4){0.f,0.f,0.f,0.f};
      sacc[m][1] = (f32x4){0.f,0.f,0.f,0.f};
    }
    __builtin_amdgcn_s_setprio(1);
    #pragma unroll
    for (int kc = 0; kc < 3; ++kc)
      #pragma unroll
      for (int m = 0; m < 8; ++m) {
        bf16x8 kf = *(const bf16x8*)(Ks + (m*16 + r15)*96 + kc*32 + g*8);
        sacc[m][0] = __builtin_amdgcn_mfma_f32_16x16x32_bf16(kf, qf[0][kc], sacc[m][0], 0,0,0);
        sacc[m][1] = __builtin_amdgcn_mfma_f32_16x16x32_bf16(kf, qf[1][kc], sacc[m][1], 0,0,0);
      }
    __builtin_amdgcn_s_setprio(0);

    #pragma unroll
    for (int n = 0; n < 2; ++n) {
      float pm = -INFINITY;
      #pragma unroll
      for (int m = 0; m < 8; ++m)
        #pragma unroll
        for (int r = 0; r < 4; ++r) pm = fmaxf(pm, sacc[m][n][r]);
      pm = fmaxf(pm, __shfl_xor(pm, 16));
      pm = fmaxf(pm, __shfl_xor(pm, 32));
      const float newm = fmaxf(mrun[n], pm);
      const float scale = __expf(mrun[n] - newm);
      mrun[n] = newm;
      const int qloc = wq*32 + n*16 + r15;
      float s = 0.f;
      #pragma unroll
      for (int m = 0; m < 8; ++m) {
        float e0 = __expf(sacc[m][n][0] - newm);
        float e1 = __expf(sacc[m][n][1] - newm);
        float e2 = __expf(sacc[m][n][2] - newm);
        float e3 = __expf(sacc[m][n][3] - newm);
        s += (e0 + e1) + (e2 + e3);
        u16x4 pk = { f2b(e0), f2b(e1), f2b(e2), f2b(e3) };
        *(u16x4*)(PsB + ((qloc*256 + m*32 + g*8) ^ swz)) = pk;
      }
      s += __shfl_xor(s, 16);
      s += __shfl_xor(s, 32);
      lrun[n] = lrun[n]*scale + s;
      #pragma unroll
      for (int m = 0; m < 6; ++m) oacc[m][n] *= scale;
    }

    #pragma unroll
    for (int kc = 0; kc < 4; ++kc) {
      bf16x8 pf0 = *(const bf16x8*)(PsB + (((wq*32      + r15)*256 + kc*64 + g*16) ^ swz));
      bf16x8 pf1 = *(const bf16x8*)(PsB + (((wq*32 + 16 + r15)*256 + kc*64 + g*16) ^ swz));
      __builtin_amdgcn_s_setprio(1);
      #pragma unroll
      for (int m = 0; m < 6; ++m) {
        bf16x8 vf = *(const bf16x8*)(VsB + (((m*16 + r15)*256 + kc*64 + g*16) ^ swz));
        oacc[m][0] = __builtin_amdgcn_mfma_f32_16x16x32_bf16(vf, pf0, oacc[m][0], 0,0,0);
        oacc[m][1] = __builtin_amdgcn_mfma_f32_16x16x32_bf16(vf, pf1, oacc[m][1], 0,0,0);
      }
      __builtin_amdgcn_s_setprio(0);
    }
    __syncthreads();
  }

  #pragma unroll
  for (int n = 0; n < 2; ++n) {
    const float inv = 1.0f / lrun[n];
    unsigned short* orow = outb + ((size_t)b*S_LEN + q0 + wq*32 + n*16 + r15)*NC + h*HD;
    #pragma unroll
    for (int m = 0; m < 6; ++m) {
      u16x4 pk = { f2b(oacc[m][n][0]*inv), f2b(oacc[m][n][1]*inv),
                   f2b(oacc[m][n][2]*inv), f2b(oacc[m][n][3]*inv) };
      *(u16x4*)(orow + m*16 + g*4) = pk;
    }
  }
}

// ---------------------------------------------------------------------------
// Weight transpose + fp32->bf16 cast: W (KxN f32) -> Wt (NxK bf16)
// ---------------------------------------------------------------------------
__global__ void transpose_cast(const float* __restrict__ W, unsigned short* __restrict__ Wt,
                               int K, int N)
{
  __shared__ float tile[32][33];
  const int tx = threadIdx.x & 31, ty = threadIdx.x >> 5;   // 32x8
  const int n0 = blockIdx.x * 32, k0 = blockIdx.y * 32;
  #pragma unroll
  for (int i = 0; i < 32; i += 8)
    tile[ty + i][tx] = W[(size_t)(k0 + ty + i)*N + n0 + tx];
  __syncthreads();
  #pragma unroll
  for (int i = 0; i < 32; i += 8)
    Wt[(size_t)(n0 + ty + i)*K + k0 + tx] = f2b(tile[tx][ty + i]);
}

// V (bf16, rows of qkv) -> Vt[d][s] per (b,h)
__global__ void transpose_v(const unsigned short* __restrict__ qkv, unsigned short* __restrict__ vt)
{
  __shared__ unsigned short tile[32][33];
  const int bh = blockIdx.z, b = bh >> 3, h = bh & 7;
  const unsigned short* v = qkv + (size_t)b*S_LEN*3*NC + 2*NC + h*HD;
  unsigned short* o = vt + (size_t)bh*HD*S_LEN;
  const int s0 = blockIdx.x * 32, d0 = blockIdx.y * 32;
  const int tx = threadIdx.x & 31, ty = threadIdx.x >> 5;
  #pragma unroll
  for (int i = 0; i < 32; i += 8)
    tile[ty + i][tx] = v[(size_t)(s0 + ty + i)*(3*NC) + d0 + tx];
  __syncthreads();
  #pragma unroll
  for (int i = 0; i < 32; i += 8)
    o[(size_t)(d0 + ty + i)*S_LEN + s0 + tx] = tile[tx][ty + i];
}

// ---------------------------------------------------------------------------
// LayerNorm over whole (S,C) plane per batch: 3-kernel pipeline
// ---------------------------------------------------------------------------
__global__ void ln_part(const float* __restrict__ X, float* __restrict__ part)
{
  const int b = blockIdx.x / 96, blk = blockIdx.x % 96;
  const float4* xb = (const float4*)(X + (size_t)b*SC);
  float s = 0.f, s2 = 0.f;
  #pragma unroll
  for (int i = 0; i < 8; ++i) {
    float4 v = xb[blk*2048 + i*256 + threadIdx.x];
    s  += v.x + v.y + v.z + v.w;
    s2 += v.x*v.x + v.y*v.y + v.z*v.z + v.w*v.w;
  }
  #pragma unroll
  for (int o = 32; o; o >>= 1) { s += __shfl_down(s, o); s2 += __shfl_down(s2, o); }
  __shared__ float r1[4], r2[4];
  const int w = threadIdx.x >> 6;
  if ((threadIdx.x & 63) == 0) { r1[w] = s; r2[w] = s2; }
  __syncthreads();
  if (threadIdx.x == 0) {
    part[(b*96 + blk)*2]     = r1[0] + r1[1] + r1[2] + r1[3];
    part[(b*96 + blk)*2 + 1] = r2[0] + r2[1] + r2[2] + r2[3];
  }
}

__global__ void ln_fin(const float* __restrict__ part, float* __restrict__ stats)
{
  const int b = blockIdx.x;
  float s = 0.f, s2 = 0.f;
  for (int i = threadIdx.x; i < 96; i += 64) {
    s  += part[(b*96 + i)*2];
    s2 += part[(b*96 + i)*2 + 1];
  }
  #pragma unroll
  for (int o = 32; o; o >>= 1) { s += __shfl_down(s, o); s2 += __shfl_down(s2, o); }
  if (threadIdx.x == 0) {
    const float inv = 1.0f / (float)SC;
    const float mu = s * inv;
    const float var = s2 * inv - mu*mu;
    stats[b*2] = mu;
    stats[b*2 + 1] = rsqrtf(var + 1e-5f);
  }
}

__global__ void ln_apply(const float* __restrict__ X, const float* __restrict__ W,
                         const float* __restrict__ Bv, const float* __restrict__ stats,
                         unsigned short* __restrict__ out)
{
  const size_t i = ((size_t)blockIdx.x*256 + threadIdx.x) * 8;
  const int b = (int)(i / SC);
  const size_t r = i % SC;
  const float mu = stats[b*2], rs = stats[b*2 + 1];
  float4 x0 = *(const float4*)(X + i),  x1 = *(const float4*)(X + i + 4);
  float4 w0 = *(const float4*)(W + r),  w1 = *(const float4*)(W + r + 4);
  float4 b0 = *(const float4*)(Bv + r), b1 = *(const float4*)(Bv + r + 4);
  u16x8 o;
  o[0] = f2b((x0.x - mu)*rs*w0.x + b0.x);
  o[1] = f2b((x0.y - mu)*rs*w0.y + b0.y);
  o[2] = f2b((x0.z - mu)*rs*w0.z + b0.z);
  o[3] = f2b((x0.w - mu)*rs*w0.w + b0.w);
  o[4] = f2b((x1.x - mu)*rs*w1.x + b1.x);
  o[5] = f2b((x1.y - mu)*rs*w1.y + b1.y);
  o[6] = f2b((x1.z - mu)*rs*w1.z + b1.z);
  o[7] = f2b((x1.w - mu)*rs*w1.w + b1.w);
  *(u16x8*)(out + i) = o;
}

// ---------------------------------------------------------------------------
extern "C" void kernel_launch(void* const* d_in, const int* in_sizes, int n_in,
                              void* d_out, int out_size, void* d_ws, size_t ws_size,
                              hipStream_t stream) {
  const float* x      = (const float*)d_in[0];
  const float* ln1_w  = (const float*)d_in[1];
  const float* ln1_b  = (const float*)d_in[2];
  const float* ln2_w  = (const float*)d_in[3];
  const float* ln2_b  = (const float*)d_in[4];
  const float* qkv_w  = (const float*)d_in[5];
  const float* proj_w = (const float*)d_in[6];
  const float* mlp_w1 = (const float*)d_in[7];
  const float* mlp_b1 = (const float*)d_in[8];
  const float* mlp_w2 = (const float*)d_in[9];
  const float* mlp_b2 = (const float*)d_in[10];
  float* out = (float*)d_out;

  char* ws = (char*)d_ws;
  size_t off = 0;
  auto alloc = [&](size_t b) { size_t o = off; off += (b + 255) & ~(size_t)255; return o; };
  unsigned short* wqkvT  = (unsigned short*)(ws + alloc((size_t)3*NC*NC*2));
  unsigned short* wprojT = (unsigned short*)(ws + alloc((size_t)NC*NC*2));
  unsigned short* w1T    = (unsigned short*)(ws + alloc((size_t)NMLP*NC*2));
  unsigned short* w2T    = (unsigned short*)(ws + alloc((size_t)NC*NMLP*2));
  unsigned short* lnbf   = (unsigned short*)(ws + alloc((size_t)BS*NC*2));       // ln1 / attnout / ln2
  const size_t qkvOff    = alloc((size_t)BS*3*NC*2);                             // 37.75 MB
  unsigned short* qkvbf  = (unsigned short*)(ws + qkvOff);
  unsigned short* vt     = (unsigned short*)(ws + alloc((size_t)NB*NH*HD*S_LEN*2)); // 12.58 MB
  unsigned short* ybf    = (unsigned short*)(ws + qkvOff);                       // overlays qkv+vt (50.33 MB)
  float* hbuf            = (float*)(ws + alloc((size_t)BS*NC*4));                // 25.17 MB
  float* part            = (float*)(ws + alloc((size_t)NB*96*2*4));
  float* stats           = (float*)(ws + alloc((size_t)NB*2*4));
  (void)ws_size; (void)in_sizes; (void)n_in; (void)out_size;

  const dim3 blk(256);
  const dim3 blk512(512);

  // weights -> bf16, transposed
  transpose_cast<<<dim3(3*NC/32, NC/32),   blk, 0, stream>>>(qkv_w,  wqkvT,  NC, 3*NC);
  transpose_cast<<<dim3(NC/32, NC/32),     blk, 0, stream>>>(proj_w, wprojT, NC, NC);
  transpose_cast<<<dim3(NMLP/32, NC/32),   blk, 0, stream>>>(mlp_w1, w1T,    NC, NMLP);
  transpose_cast<<<dim3(NC/32, NMLP/32),   blk, 0, stream>>>(mlp_w2, w2T,    NMLP, NC);

  // LN1
  ln_part<<<dim3(NB*96), blk, 0, stream>>>(x, part);
  ln_fin<<<dim3(NB), dim3(64), 0, stream>>>(part, stats);
  ln_apply<<<dim3(BS*NC/2048), blk, 0, stream>>>(x, ln1_w, ln1_b, stats, lnbf);

  // QKV GEMM: (8192x768)@(768x2304) -> bf16
  gemm8<0><<<dim3(BS/128, 3*NC/256), blk512, 0, stream>>>(
      lnbf, NC, wqkvT, NC, qkvbf, 3*NC, NC, nullptr, nullptr, 0);

  // V -> Vt
  transpose_v<<<dim3(S_LEN/32, HD/32, NB*NH), blk, 0, stream>>>(qkvbf, vt);

  // flash attention -> lnbf (attention output, bf16)
  flash_attn<<<dim3(S_LEN/128, NB*NH), blk, 0, stream>>>(qkvbf, vt, lnbf);

  // proj + residual x -> h (f32)
  gemm8<3><<<dim3(BS/128, NC/256), blk512, 0, stream>>>(
      lnbf, NC, wprojT, NC, hbuf, NC, NC, nullptr, x, NC);

  // LN2 on h
  ln_part<<<dim3(NB*96), blk, 0, stream>>>(hbuf, part);
  ln_fin<<<dim3(NB), dim3(64), 0, stream>>>(part, stats);
  ln_apply<<<dim3(BS*NC/2048), blk, 0, stream>>>(hbuf, ln2_w, ln2_b, stats, lnbf);

  // MLP1: +bias, GELU -> bf16
  gemm8<2><<<dim3(BS/128, NMLP/256), blk512, 0, stream>>>(
      lnbf, NC, w1T, NC, ybf, NMLP, NC, mlp_b1, nullptr, 0);

  // MLP2: +bias +residual h -> out (f32)
  gemm8<4><<<dim3(BS/128, NC/256), blk512, 0, stream>>>(
      ybf, NMLP, w2T, NMLP, out, NC, NMLP, mlp_b2, hbuf, NC);
}

// Round 4
// 282.918 us; speedup vs baseline: 1.1487x; 1.1487x over previous
//
#include <hip/hip_runtime.h>
#include <hip/hip_bf16.h>

#define S_LEN 1024
#define NB 8
#define NC 768
#define NH 8
#define HD 96
#define NMLP 3072
#define SC (S_LEN*NC)        // 786432
#define BS (NB*S_LEN)        // 8192

typedef __attribute__((ext_vector_type(8))) unsigned short u16x8;
typedef __attribute__((ext_vector_type(4))) unsigned short u16x4;
typedef __attribute__((ext_vector_type(8))) __bf16 bf16x8;
typedef __attribute__((ext_vector_type(4))) float f32x4;

__device__ __forceinline__ unsigned short f2b(float f) {
  union { __hip_bfloat16 h; unsigned short u; } cvt;
  cvt.h = __float2bfloat16(f);
  return cvt.u;
}

// async global->LDS, 16B per lane. LDS dest = wave-uniform base + lane*16.
__device__ __forceinline__ void gload16(const unsigned short* g, unsigned short* l) {
  __builtin_amdgcn_global_load_lds(
      (const __attribute__((address_space(1))) unsigned int*)g,
      (__attribute__((address_space(3))) unsigned int*)l, 16, 0, 0);
}

// overflow-safe tanh-form GELU (abs err < 3e-4 vs exact erf GELU)
__device__ __forceinline__ float gelu_f(float v) {
  float u = v * (0.7978845608f + 0.0356774081f * v * v);
  float au = fabsf(u);
  float e = __expf(-2.0f * au);
  float th = (1.0f - e) / (1.0f + e);
  th = copysignf(th, u);
  return 0.5f * v * (1.0f + th);
}

// ---------------------------------------------------------------------------
// Phase-locked pipelined bf16 GEMM (m201-style schedule).
// C = A(MxK) * B(KxN), B given TRANSPOSED (Bt: NxK).
// BM=256, BN=128, BK=64. 8 waves (4M x 2N), per-wave 64x64 (acc[4][4]).
// 3-buffer LDS ring (144 KB): compute tile t while t+1 resident, t+2 in
// flight. Per K-tile: 2 phases, each = {ds_read frags, 3x global_load_lds,
// s_barrier, lgkmcnt(0), setprio(1), 16 MFMA, setprio(0), s_barrier}.
// vmcnt(6) once per K-tile (counted, never 0 in steady state).
// LDS XOR-swizzle: 16B-chunk ^= row&7 (inverse-swizzled source + swizzled
// ds_read, both-sides involution; round-3 verified 0 bank conflicts).
// EPI: 0 = store bf16; 2 = +bias,GELU,bf16; 3 = +residual,f32; 4 = +bias+res,f32
// ---------------------------------------------------------------------------
template<int EPI>
__global__ __launch_bounds__(512, 1)
void gemm8(const unsigned short* __restrict__ A, int lda,
           const unsigned short* __restrict__ Bt, int ldb,
           void* __restrict__ Cv, int ldc, int K,
           const float* __restrict__ bias,
           const float* __restrict__ residual, int ldr)
{
  __shared__ unsigned short As[3*16384];   // 3 x [256][64] bf16 (swizzled)
  __shared__ unsigned short Bs[3*8192];    // 3 x [128][64] bf16 (swizzled)
  const int tid = threadIdx.x, lane = tid & 63, wid = tid >> 6;
  const int wm = wid & 3, wn = wid >> 2;
  const int r15 = lane & 15, g = lane >> 4;
  const int tm = blockIdx.x * 256, tn = blockIdx.y * 128;
  const int NT = K >> 6;

  // staging source (inverse-swizzled): lane l -> LDS row base + (l>>3),
  // stored 16B chunk (l&7); global chunk = (l&7) ^ (l>>3).
  const int srow = lane >> 3;
  const int scol = ((lane & 7) ^ srow) << 3;
  const unsigned short* Ag = A  + (size_t)(tm + wid*32 + srow)*lda + scol;
  const unsigned short* Bg = Bt + (size_t)(tn + wid*16 + srow)*ldb + scol;

  // swizzled read offsets (bytes within a 128B row)
  const int kx  = (r15 & 7) << 4;
  const int k0b = (g*16) ^ kx;
  const int k1b = (64 + g*16) ^ kx;
  char* AsB = (char*)As;
  char* BsB = (char*)Bs;
  const int arow = (wm*64 + r15) * 128;
  const int brow = (wn*64 + r15) * 128;

#define LDA8(m,ks) (*(const bf16x8*)(AsB + bufA + arow + (m)*2048 + ((ks) ? k1b : k0b)))
#define LDB8(n,ks) (*(const bf16x8*)(BsB + bufB + brow + (n)*2048 + ((ks) ? k1b : k0b)))
#define STGA(i,kk,bf) gload16(Ag + (size_t)((i)*8)*lda + (kk), As + (bf)*16384 + (wid*4 + (i))*512)
#define STGB(i,kk,bf) gload16(Bg + (size_t)((i)*8)*ldb + (kk), Bs + (bf)*8192  + (wid*2 + (i))*512)
#define MFMA16(a8,b8,c) __builtin_amdgcn_mfma_f32_16x16x32_bf16(a8, b8, c, 0, 0, 0)

  f32x4 acc[4][4];
  #pragma unroll
  for (int m = 0; m < 4; ++m)
    #pragma unroll
    for (int n = 0; n < 4; ++n)
      acc[m][n] = (f32x4){0.f, 0.f, 0.f, 0.f};

  // prologue: stage tiles 0 and 1; wait tile 0 (tile 1's 6 stay in flight)
  STGA(0,0,0); STGA(1,0,0); STGA(2,0,0); STGA(3,0,0); STGB(0,0,0); STGB(1,0,0);
  STGA(0,64,1); STGA(1,64,1); STGA(2,64,1); STGA(3,64,1); STGB(0,64,1); STGB(1,64,1);
  asm volatile("s_waitcnt vmcnt(6)" ::: "memory");
  __builtin_amdgcn_s_barrier();

  int buf = 0, nbuf = 2;
  for (int t = 0; t < NT; ++t) {
    const int kk = (t + 2) << 6;
    const bool pre = (t + 2) < NT;
    const int bufA = buf * 32768;   // bytes
    const int bufB = buf * 16384;
    bf16x8 a[4][2], b0[2][2], b1[2][2];

    // ======== phase 0: read A(4mx2ks)+B(n0,n1); stage 3; MFMA n01 ========
    #pragma unroll
    for (int m = 0; m < 4; ++m) { a[m][0] = LDA8(m,0); a[m][1] = LDA8(m,1); }
    #pragma unroll
    for (int n = 0; n < 2; ++n) { b0[n][0] = LDB8(n,0); b0[n][1] = LDB8(n,1); }
    if (pre) { STGA(0,kk,nbuf); STGA(1,kk,nbuf); STGB(0,kk,nbuf); }
    __builtin_amdgcn_s_barrier();
    asm volatile("s_waitcnt lgkmcnt(0)" ::: "memory");
    __builtin_amdgcn_s_setprio(1);
    #pragma unroll
    for (int m = 0; m < 4; ++m)
      #pragma unroll
      for (int n = 0; n < 2; ++n) {
        acc[m][n] = MFMA16(a[m][0], b0[n][0], acc[m][n]);
        acc[m][n] = MFMA16(a[m][1], b0[n][1], acc[m][n]);
      }
    __builtin_amdgcn_s_setprio(0);
    __builtin_amdgcn_s_barrier();

    // ======== phase 1: read B(n2,n3); stage 3; MFMA n23; vmcnt(6) ========
    #pragma unroll
    for (int n = 0; n < 2; ++n) { b1[n][0] = LDB8(n+2,0); b1[n][1] = LDB8(n+2,1); }
    if (pre) { STGA(2,kk,nbuf); STGA(3,kk,nbuf); STGB(1,kk,nbuf); }
    __builtin_amdgcn_s_barrier();
    asm volatile("s_waitcnt lgkmcnt(0)" ::: "memory");
    __builtin_amdgcn_s_setprio(1);
    #pragma unroll
    for (int m = 0; m < 4; ++m)
      #pragma unroll
      for (int n = 0; n < 2; ++n) {
        acc[m][n+2] = MFMA16(a[m][0], b1[n][0], acc[m][n+2]);
        acc[m][n+2] = MFMA16(a[m][1], b1[n][1], acc[m][n+2]);
      }
    __builtin_amdgcn_s_setprio(0);
    if (pre) asm volatile("s_waitcnt vmcnt(6)" ::: "memory");
    else     asm volatile("s_waitcnt vmcnt(0)" ::: "memory");
    __builtin_amdgcn_s_barrier();
    buf  = (buf  == 2) ? 0 : buf  + 1;
    nbuf = (nbuf == 2) ? 0 : nbuf + 1;
  }
#undef LDA8
#undef LDB8
#undef STGA
#undef STGB
#undef MFMA16

  unsigned short* Cu = (unsigned short*)Cv;
  float* Cf = (float*)Cv;
  #pragma unroll
  for (int m = 0; m < 4; ++m) {
    #pragma unroll
    for (int n = 0; n < 4; ++n) {
      const int col = tn + wn*64 + n*16 + r15;
      #pragma unroll
      for (int r = 0; r < 4; ++r) {
        const int row = tm + wm*64 + m*16 + g*4 + r;
        float v = acc[m][n][r];
        if (EPI == 2 || EPI == 4) v += bias[col];
        if (EPI == 3 || EPI == 4) v += residual[(size_t)row*ldr + col];
        if (EPI == 2) v = gelu_f(v);
        if (EPI == 0 || EPI == 2) Cu[(size_t)row*ldc + col] = f2b(v);
        else                      Cf[(size_t)row*ldc + col] = v;
      }
    }
  }
}

// ---------------------------------------------------------------------------
// Flash attention, one (b,h) x 128-q-row tile per block, 4 waves.
// ---------------------------------------------------------------------------
__global__ __launch_bounds__(256, 2)
void flash_attn(const unsigned short* __restrict__ qkv,   // [B][S][2304] bf16
                const unsigned short* __restrict__ vt,    // [B*H][96][1024] bf16
                unsigned short* __restrict__ outb)        // [B][S][768] bf16
{
  __shared__ unsigned short Ks[128*96];
  __shared__ unsigned short Vs[96*128];
  __shared__ unsigned short Ps[128*128];
  const int tid = threadIdx.x, lane = tid & 63, wq = tid >> 6;
  const int r15 = lane & 15, g = lane >> 4;
  const int bh = blockIdx.y, b = bh >> 3, h = bh & 7;
  const int q0 = blockIdx.x * 128;
  const int swz = (r15 & 7) << 4;
  char* PsB = (char*)Ps;
  char* VsB = (char*)Vs;

  bf16x8 qf[2][3];
  {
    const unsigned short* qb = qkv + ((size_t)b*S_LEN + q0 + wq*32 + r15)*2304 + h*HD + g*8;
    #pragma unroll
    for (int n = 0; n < 2; ++n)
      #pragma unroll
      for (int kc = 0; kc < 3; ++kc)
        qf[n][kc] = *(const bf16x8*)(qb + (size_t)n*16*2304 + kc*32);
  }

  int krow[6], kcol[6], vrow[6], vcol[6];
  #pragma unroll
  for (int i = 0; i < 6; ++i) {
    const int c = (wq*6 + i)*64 + lane;
    krow[i] = c / 12;
    kcol[i] = (c % 12) * 8;
    const int L = c * 16;
    const int row = L >> 8, cb = L & 255;
    vrow[i] = row;
    vcol[i] = (cb ^ ((row & 7) << 4)) >> 1;
  }
  const unsigned short* kbase = qkv + (size_t)b*S_LEN*2304 + NC + h*HD;
  const unsigned short* vbase = vt + (size_t)bh*HD*S_LEN;

  f32x4 oacc[6][2];
  #pragma unroll
  for (int m = 0; m < 6; ++m) {
    oacc[m][0] = (f32x4){0.f,0.f,0.f,0.f};
    oacc[m][1] = (f32x4){0.f,0.f,0.f,0.f};
  }
  float mrun[2] = {-INFINITY, -INFINITY};
  float lrun[2] = {0.f, 0.f};

  for (int kt = 0; kt < 8; ++kt) {
    const unsigned short* ksrc = kbase + (size_t)kt*128*2304;
    const unsigned short* vsrc = vbase + kt*128;
    #pragma unroll
    for (int i = 0; i < 6; ++i) {
      gload16(ksrc + (size_t)krow[i]*2304 + kcol[i], Ks + (wq*6 + i)*512);
      gload16(vsrc + vrow[i]*1024 + vcol[i],         Vs + (wq*6 + i)*512);
    }
    __syncthreads();

    f32x4 sacc[8][2];
    #pragma unroll
    for (int m = 0; m < 8; ++m) {
      sacc[m][0] = (f32x4){0.f,0.f,0.f,0.f};
      sacc[m][1] = (f32x4){0.f,0.f,0.f,0.f};
    }
    __builtin_amdgcn_s_setprio(1);
    #pragma unroll
    for (int kc = 0; kc < 3; ++kc)
      #pragma unroll
      for (int m = 0; m < 8; ++m) {
        bf16x8 kf = *(const bf16x8*)(Ks + (m*16 + r15)*96 + kc*32 + g*8);
        sacc[m][0] = __builtin_amdgcn_mfma_f32_16x16x32_bf16(kf, qf[0][kc], sacc[m][0], 0,0,0);
        sacc[m][1] = __builtin_amdgcn_mfma_f32_16x16x32_bf16(kf, qf[1][kc], sacc[m][1], 0,0,0);
      }
    __builtin_amdgcn_s_setprio(0);

    #pragma unroll
    for (int n = 0; n < 2; ++n) {
      float pm = -INFINITY;
      #pragma unroll
      for (int m = 0; m < 8; ++m)
        #pragma unroll
        for (int r = 0; r < 4; ++r) pm = fmaxf(pm, sacc[m][n][r]);
      pm = fmaxf(pm, __shfl_xor(pm, 16));
      pm = fmaxf(pm, __shfl_xor(pm, 32));
      const float newm = fmaxf(mrun[n], pm);
      const float scale = __expf(mrun[n] - newm);
      mrun[n] = newm;
      const int qloc = wq*32 + n*16 + r15;
      float s = 0.f;
      #pragma unroll
      for (int m = 0; m < 8; ++m) {
        float e0 = __expf(sacc[m][n][0] - newm);
        float e1 = __expf(sacc[m][n][1] - newm);
        float e2 = __expf(sacc[m][n][2] - newm);
        float e3 = __expf(sacc[m][n][3] - newm);
        s += (e0 + e1) + (e2 + e3);
        u16x4 pk = { f2b(e0), f2b(e1), f2b(e2), f2b(e3) };
        *(u16x4*)(PsB + ((qloc*256 + m*32 + g*8) ^ swz)) = pk;
      }
      s += __shfl_xor(s, 16);
      s += __shfl_xor(s, 32);
      lrun[n] = lrun[n]*scale + s;
      #pragma unroll
      for (int m = 0; m < 6; ++m) oacc[m][n] *= scale;
    }

    #pragma unroll
    for (int kc = 0; kc < 4; ++kc) {
      bf16x8 pf0 = *(const bf16x8*)(PsB + (((wq*32      + r15)*256 + kc*64 + g*16) ^ swz));
      bf16x8 pf1 = *(const bf16x8*)(PsB + (((wq*32 + 16 + r15)*256 + kc*64 + g*16) ^ swz));
      __builtin_amdgcn_s_setprio(1);
      #pragma unroll
      for (int m = 0; m < 6; ++m) {
        bf16x8 vf = *(const bf16x8*)(VsB + (((m*16 + r15)*256 + kc*64 + g*16) ^ swz));
        oacc[m][0] = __builtin_amdgcn_mfma_f32_16x16x32_bf16(vf, pf0, oacc[m][0], 0,0,0);
        oacc[m][1] = __builtin_amdgcn_mfma_f32_16x16x32_bf16(vf, pf1, oacc[m][1], 0,0,0);
      }
      __builtin_amdgcn_s_setprio(0);
    }
    __syncthreads();
  }

  #pragma unroll
  for (int n = 0; n < 2; ++n) {
    const float inv = 1.0f / lrun[n];
    unsigned short* orow = outb + ((size_t)b*S_LEN + q0 + wq*32 + n*16 + r15)*NC + h*HD;
    #pragma unroll
    for (int m = 0; m < 6; ++m) {
      u16x4 pk = { f2b(oacc[m][n][0]*inv), f2b(oacc[m][n][1]*inv),
                   f2b(oacc[m][n][2]*inv), f2b(oacc[m][n][3]*inv) };
      *(u16x4*)(orow + m*16 + g*4) = pk;
    }
  }
}

// ---------------------------------------------------------------------------
// Weight transpose + fp32->bf16 cast: W (KxN f32) -> Wt (NxK bf16)
// ---------------------------------------------------------------------------
__global__ void transpose_cast(const float* __restrict__ W, unsigned short* __restrict__ Wt,
                               int K, int N)
{
  __shared__ float tile[32][33];
  const int tx = threadIdx.x & 31, ty = threadIdx.x >> 5;   // 32x8
  const int n0 = blockIdx.x * 32, k0 = blockIdx.y * 32;
  #pragma unroll
  for (int i = 0; i < 32; i += 8)
    tile[ty + i][tx] = W[(size_t)(k0 + ty + i)*N + n0 + tx];
  __syncthreads();
  #pragma unroll
  for (int i = 0; i < 32; i += 8)
    Wt[(size_t)(n0 + ty + i)*K + k0 + tx] = f2b(tile[tx][ty + i]);
}

// V (bf16, rows of qkv) -> Vt[d][s] per (b,h)
__global__ void transpose_v(const unsigned short* __restrict__ qkv, unsigned short* __restrict__ vt)
{
  __shared__ unsigned short tile[32][33];
  const int bh = blockIdx.z, b = bh >> 3, h = bh & 7;
  const unsigned short* v = qkv + (size_t)b*S_LEN*3*NC + 2*NC + h*HD;
  unsigned short* o = vt + (size_t)bh*HD*S_LEN;
  const int s0 = blockIdx.x * 32, d0 = blockIdx.y * 32;
  const int tx = threadIdx.x & 31, ty = threadIdx.x >> 5;
  #pragma unroll
  for (int i = 0; i < 32; i += 8)
    tile[ty + i][tx] = v[(size_t)(s0 + ty + i)*(3*NC) + d0 + tx];
  __syncthreads();
  #pragma unroll
  for (int i = 0; i < 32; i += 8)
    o[(size_t)(d0 + ty + i)*S_LEN + s0 + tx] = tile[tx][ty + i];
}

// ---------------------------------------------------------------------------
// LayerNorm over whole (S,C) plane per batch: 3-kernel pipeline
// ---------------------------------------------------------------------------
__global__ void ln_part(const float* __restrict__ X, float* __restrict__ part)
{
  const int b = blockIdx.x / 96, blk = blockIdx.x % 96;
  const float4* xb = (const float4*)(X + (size_t)b*SC);
  float s = 0.f, s2 = 0.f;
  #pragma unroll
  for (int i = 0; i < 8; ++i) {
    float4 v = xb[blk*2048 + i*256 + threadIdx.x];
    s  += v.x + v.y + v.z + v.w;
    s2 += v.x*v.x + v.y*v.y + v.z*v.z + v.w*v.w;
  }
  #pragma unroll
  for (int o = 32; o; o >>= 1) { s += __shfl_down(s, o); s2 += __shfl_down(s2, o); }
  __shared__ float r1[4], r2[4];
  const int w = threadIdx.x >> 6;
  if ((threadIdx.x & 63) == 0) { r1[w] = s; r2[w] = s2; }
  __syncthreads();
  if (threadIdx.x == 0) {
    part[(b*96 + blk)*2]     = r1[0] + r1[1] + r1[2] + r1[3];
    part[(b*96 + blk)*2 + 1] = r2[0] + r2[1] + r2[2] + r2[3];
  }
}

__global__ void ln_fin(const float* __restrict__ part, float* __restrict__ stats)
{
  const int b = blockIdx.x;
  float s = 0.f, s2 = 0.f;
  for (int i = threadIdx.x; i < 96; i += 64) {
    s  += part[(b*96 + i)*2];
    s2 += part[(b*96 + i)*2 + 1];
  }
  #pragma unroll
  for (int o = 32; o; o >>= 1) { s += __shfl_down(s, o); s2 += __shfl_down(s2, o); }
  if (threadIdx.x == 0) {
    const float inv = 1.0f / (float)SC;
    const float mu = s * inv;
    const float var = s2 * inv - mu*mu;
    stats[b*2] = mu;
    stats[b*2 + 1] = rsqrtf(var + 1e-5f);
  }
}

__global__ void ln_apply(const float* __restrict__ X, const float* __restrict__ W,
                         const float* __restrict__ Bv, const float* __restrict__ stats,
                         unsigned short* __restrict__ out)
{
  const size_t i = ((size_t)blockIdx.x*256 + threadIdx.x) * 8;
  const int b = (int)(i / SC);
  const size_t r = i % SC;
  const float mu = stats[b*2], rs = stats[b*2 + 1];
  float4 x0 = *(const float4*)(X + i),  x1 = *(const float4*)(X + i + 4);
  float4 w0 = *(const float4*)(W + r),  w1 = *(const float4*)(W + r + 4);
  float4 b0 = *(const float4*)(Bv + r), b1 = *(const float4*)(Bv + r + 4);
  u16x8 o;
  o[0] = f2b((x0.x - mu)*rs*w0.x + b0.x);
  o[1] = f2b((x0.y - mu)*rs*w0.y + b0.y);
  o[2] = f2b((x0.z - mu)*rs*w0.z + b0.z);
  o[3] = f2b((x0.w - mu)*rs*w0.w + b0.w);
  o[4] = f2b((x1.x - mu)*rs*w1.x + b1.x);
  o[5] = f2b((x1.y - mu)*rs*w1.y + b1.y);
  o[6] = f2b((x1.z - mu)*rs*w1.z + b1.z);
  o[7] = f2b((x1.w - mu)*rs*w1.w + b1.w);
  *(u16x8*)(out + i) = o;
}

// ---------------------------------------------------------------------------
extern "C" void kernel_launch(void* const* d_in, const int* in_sizes, int n_in,
                              void* d_out, int out_size, void* d_ws, size_t ws_size,
                              hipStream_t stream) {
  const float* x      = (const float*)d_in[0];
  const float* ln1_w  = (const float*)d_in[1];
  const float* ln1_b  = (const float*)d_in[2];
  const float* ln2_w  = (const float*)d_in[3];
  const float* ln2_b  = (const float*)d_in[4];
  const float* qkv_w  = (const float*)d_in[5];
  const float* proj_w = (const float*)d_in[6];
  const float* mlp_w1 = (const float*)d_in[7];
  const float* mlp_b1 = (const float*)d_in[8];
  const float* mlp_w2 = (const float*)d_in[9];
  const float* mlp_b2 = (const float*)d_in[10];
  float* out = (float*)d_out;

  char* ws = (char*)d_ws;
  size_t off = 0;
  auto alloc = [&](size_t b) { size_t o = off; off += (b + 255) & ~(size_t)255; return o; };
  unsigned short* wqkvT  = (unsigned short*)(ws + alloc((size_t)3*NC*NC*2));
  unsigned short* wprojT = (unsigned short*)(ws + alloc((size_t)NC*NC*2));
  unsigned short* w1T    = (unsigned short*)(ws + alloc((size_t)NMLP*NC*2));
  unsigned short* w2T    = (unsigned short*)(ws + alloc((size_t)NC*NMLP*2));
  unsigned short* lnbf   = (unsigned short*)(ws + alloc((size_t)BS*NC*2));       // ln1 / attnout / ln2
  const size_t qkvOff    = alloc((size_t)BS*3*NC*2);                             // 37.75 MB
  unsigned short* qkvbf  = (unsigned short*)(ws + qkvOff);
  unsigned short* vt     = (unsigned short*)(ws + alloc((size_t)NB*NH*HD*S_LEN*2)); // 12.58 MB
  unsigned short* ybf    = (unsigned short*)(ws + qkvOff);                       // overlays qkv+vt (50.33 MB)
  float* hbuf            = (float*)(ws + alloc((size_t)BS*NC*4));                // 25.17 MB
  float* part            = (float*)(ws + alloc((size_t)NB*96*2*4));
  float* stats           = (float*)(ws + alloc((size_t)NB*2*4));
  (void)ws_size; (void)in_sizes; (void)n_in; (void)out_size;

  const dim3 blk(256);
  const dim3 blk512(512);

  // weights -> bf16, transposed
  transpose_cast<<<dim3(3*NC/32, NC/32),   blk, 0, stream>>>(qkv_w,  wqkvT,  NC, 3*NC);
  transpose_cast<<<dim3(NC/32, NC/32),     blk, 0, stream>>>(proj_w, wprojT, NC, NC);
  transpose_cast<<<dim3(NMLP/32, NC/32),   blk, 0, stream>>>(mlp_w1, w1T,    NC, NMLP);
  transpose_cast<<<dim3(NC/32, NMLP/32),   blk, 0, stream>>>(mlp_w2, w2T,    NMLP, NC);

  // LN1
  ln_part<<<dim3(NB*96), blk, 0, stream>>>(x, part);
  ln_fin<<<dim3(NB), dim3(64), 0, stream>>>(part, stats);
  ln_apply<<<dim3(BS*NC/2048), blk, 0, stream>>>(x, ln1_w, ln1_b, stats, lnbf);

  // QKV GEMM: (8192x768)@(768x2304) -> bf16
  gemm8<0><<<dim3(BS/256, 3*NC/128), blk512, 0, stream>>>(
      lnbf, NC, wqkvT, NC, qkvbf, 3*NC, NC, nullptr, nullptr, 0);

  // V -> Vt
  transpose_v<<<dim3(S_LEN/32, HD/32, NB*NH), blk, 0, stream>>>(qkvbf, vt);

  // flash attention -> lnbf (attention output, bf16)
  flash_attn<<<dim3(S_LEN/128, NB*NH), blk, 0, stream>>>(qkvbf, vt, lnbf);

  // proj + residual x -> h (f32)
  gemm8<3><<<dim3(BS/256, NC/128), blk512, 0, stream>>>(
      lnbf, NC, wprojT, NC, hbuf, NC, NC, nullptr, x, NC);

  // LN2 on h
  ln_part<<<dim3(NB*96), blk, 0, stream>>>(hbuf, part);
  ln_fin<<<dim3(NB), dim3(64), 0, stream>>>(part, stats);
  ln_apply<<<dim3(BS*NC/2048), blk, 0, stream>>>(hbuf, ln2_w, ln2_b, stats, lnbf);

  // MLP1: +bias, GELU -> bf16
  gemm8<2><<<dim3(BS/256, NMLP/128), blk512, 0, stream>>>(
      lnbf, NC, w1T, NC, ybf, NMLP, NC, mlp_b1, nullptr, 0);

  // MLP2: +bias +residual h -> out (f32)
  gemm8<4><<<dim3(BS/256, NC/128), blk512, 0, stream>>>(
      ybf, NMLP, w2T, NMLP, out, NC, NMLP, mlp_b2, hbuf, NC);
}